// Round 9
// baseline (85.387 us; speedup 1.0000x reference)
//
#include <hip/hip_runtime.h>
#include <hip/hip_bf16.h>

// RoI crop: out[n,b,i,j,c] = features[b, x1(n)+i, y1(n)+j, c]
// features: [B=8, 64, 64, C=256] f32 ; boxes: [N=1000, 4] i32 (x1,y1,x2,y2)
// out: [N, B, 7, 7, C] f32  (401 MB streaming write)
//
// R8: split the write stream across BOTH store paths. Evidence so far:
//   - reads must be XCD-L2-pinned (R6: reads via L3/HBM = 152us)
//   - all-plain stores evict the exactly-4MB read slice (R4: 95us)
//   - all-nt stores cap at ~5.2 TB/s (R3/R5/R7 plateau; fill's L2
//     write-back path does 6.9 TB/s)
// Alternate rows plain/nt inside every wave: ~half the writes use the
// 6.9 TB/s L2-writeback path, half the 5.2 TB/s bypass path, and L2
// pollution is halved vs R4 (feature lines re-referenced ~100x should
// survive LRU; misses fall to L3, not HBM).
//  - R7 fire-and-forget structure kept: all loads -> one vmcnt (loads
//    only) -> all stores -> s_endpgm with stores in flight.
//  - Block = one (n,b) plane; 4 waves take rows [13,12,12,12] of 49.

#define ANCHOR 7
#define FS     64
#define NBOX   1000
#define BB     8
#define CC     256
#define C4     (CC / 4)                 // 64 f32x4 per 1KB row
#define ROWS   (BB * ANCHOR * ANCHOR)   // 392 rows per box
#define MAXR   13

typedef float f32x4 __attribute__((ext_vector_type(4)));

__global__ __launch_bounds__(256) void roi_crop_kernel(
    const f32x4* __restrict__ fin,      // features as f32x4
    const int*   __restrict__ boxes,    // [N,4]
    f32x4*       __restrict__ fout)     // out as f32x4
{
    const int lane = threadIdx.x & 63;
    const int wave = threadIdx.x >> 6;          // 0..3
    const int x    = blockIdx.x;                // 0..7999
    const int b    = x & 7;                     // batch slice == XCD id
    const int n    = x >> 3;                    // box index, 0..999

    int x1 = boxes[n * 4 + 0];
    int y1 = boxes[n * 4 + 1];
    x1 = min(max(x1, 0), FS - ANCHOR);
    y1 = min(max(y1, 0), FS - ANCHOR);

    // rows [start, start+cnt) of the 49-row (n,b) plane; wave-uniform
    const int start = (wave == 0) ? 0 : 1 + 12 * wave;   // 0,13,25,37
    const int cnt   = (wave == 0) ? 13 : 12;

    const f32x4* __restrict__ src = fin + ((b * FS + x1) * FS + y1) * C4 + lane;
    f32x4* __restrict__ dst = fout + n * (ROWS * C4) + b * (ANCHOR * ANCHOR * C4)
                              + start * C4 + lane;

    f32x4 buf[MAXR];

    // phase 1: issue ALL loads (vmcnt queue = loads only)
    #pragma unroll
    for (int t = 0; t < MAXR; ++t) {
        if (t < cnt) {                       // wave-uniform branch
            int r = start + t;
            int i = r / ANCHOR;
            int j = r - i * ANCHOR;
            buf[t] = src[(i * FS + j) * C4];
        }
    }

    // phase 2: stores alternate between the two write paths per row:
    // even t -> nontemporal (L2-bypass), odd t -> plain (L2 write-back).
    // Wave retires with stores in flight (never waited on).
    #pragma unroll
    for (int t = 0; t < MAXR; ++t) {
        if (t < cnt) {
            if (t & 1)
                dst[t * C4] = buf[t];                               // plain
            else
                __builtin_nontemporal_store(buf[t], &dst[t * C4]);  // nt
        }
    }
}

extern "C" void kernel_launch(void* const* d_in, const int* in_sizes, int n_in,
                              void* d_out, int out_size, void* d_ws, size_t ws_size,
                              hipStream_t stream) {
    const f32x4* fin  = (const f32x4*)d_in[0];
    const int*  boxes = (const int*)d_in[1];
    f32x4*      fout  = (f32x4*)d_out;

    roi_crop_kernel<<<NBOX * BB, 256, 0, stream>>>(fin, boxes, fout);
}

// Round 10
// 76.553 us; speedup vs baseline: 1.1154x; 1.1154x over previous
//
#include <hip/hip_runtime.h>
#include <hip/hip_bf16.h>

// RoI crop: out[n,b,i,j,c] = features[b, x1(n)+i, y1(n)+j, c]
// features: [B=8, 64, 64, C=256] f32 ; boxes: [N=1000, 4] i32 (x1,y1,x2,y2)
// out: [N, B, 7, 7, C] f32  (401 MB streaming write)
//
// R9: R7 (fire-and-forget, XCD-pinned reads, nt stores) with HALVED
// per-wave footprint for full occupancy. R7's wave0 held buf[13] (52 data
// VGPRs, ~70 total) -> occupancy clipped at the 64-VGPR step. Here each
// block does half a (n,b) plane; waves hold <=7 rows (28 VGPRs, ~45
// total) -> 8 waves/SIMD; 16000 blocks -> finer CU balance.
// Settled by R4/R6/R8: stores must be nt (plain thrashes the pinned 4MB
// read slice); reads must be L2-pinned (L3 reads = 152us).
//  - b = blockIdx&7 keeps the XCD round-robin pin exact.

#define ANCHOR 7
#define FS     64
#define NBOX   1000
#define BB     8
#define CC     256
#define C4     (CC / 4)                 // 64 f32x4 per 1KB row
#define ROWS   (BB * ANCHOR * ANCHOR)   // 392 rows per box
#define MAXR   7

typedef float f32x4 __attribute__((ext_vector_type(4)));

__global__ __launch_bounds__(256) void roi_crop_kernel(
    const f32x4* __restrict__ fin,      // features as f32x4
    const int*   __restrict__ boxes,    // [N,4]
    f32x4*       __restrict__ fout)     // out as f32x4
{
    const int lane = threadIdx.x & 63;
    const int wave = threadIdx.x >> 6;          // 0..3
    const int x    = blockIdx.x;                // 0..15999
    const int b    = x & 7;                     // batch slice == XCD id
    const int u    = x >> 3;                    // 0..1999
    const int n    = u >> 1;                    // box index, 0..999
    const int half = u & 1;                     // which half of the 49 rows

    int x1 = boxes[n * 4 + 0];
    int y1 = boxes[n * 4 + 1];
    x1 = min(max(x1, 0), FS - ANCHOR);
    y1 = min(max(y1, 0), FS - ANCHOR);

    // half 0: rows [0,25) as [7,6,6,6]; half 1: rows [25,49) as [6,6,6,6]
    const int start = half ? (25 + 6 * wave)
                           : (wave ? 1 + 6 * wave : 0);
    const int cnt   = (!half && wave == 0) ? 7 : 6;

    const f32x4* __restrict__ src = fin + ((b * FS + x1) * FS + y1) * C4 + lane;
    f32x4* __restrict__ dst = fout + n * (ROWS * C4) + b * (ANCHOR * ANCHOR * C4)
                              + start * C4 + lane;

    f32x4 buf[MAXR];

    // phase 1: issue ALL loads (vmcnt queue = loads only)
    #pragma unroll
    for (int t = 0; t < MAXR; ++t) {
        if (t < cnt) {                       // wave-uniform branch
            int r = start + t;
            int i = r / ANCHOR;
            int j = r - i * ANCHOR;
            buf[t] = src[(i * FS + j) * C4];
        }
    }

    // phase 2: all nt stores; wave retires with stores in flight.
    #pragma unroll
    for (int t = 0; t < MAXR; ++t) {
        if (t < cnt)
            __builtin_nontemporal_store(buf[t], &dst[t * C4]);
    }
}

extern "C" void kernel_launch(void* const* d_in, const int* in_sizes, int n_in,
                              void* d_out, int out_size, void* d_ws, size_t ws_size,
                              hipStream_t stream) {
    const f32x4* fin  = (const f32x4*)d_in[0];
    const int*  boxes = (const int*)d_in[1];
    f32x4*      fout  = (f32x4*)d_out;

    roi_crop_kernel<<<NBOX * BB * 2, 256, 0, stream>>>(fin, boxes, fout);
}